// Round 8
// baseline (239.243 us; speedup 1.0000x reference)
//
#include <hip/hip_runtime.h>
#include <math.h>

typedef __attribute__((ext_vector_type(8)))  __bf16   bf16x8;
typedef __attribute__((ext_vector_type(4)))  float    f32x4;
typedef __attribute__((ext_vector_type(16))) float    f32x16;
typedef __attribute__((ext_vector_type(4)))  unsigned u32x4;
typedef __attribute__((ext_vector_type(2)))  unsigned u32x2;

__device__ __forceinline__ unsigned short f2bf(float f) {
    unsigned u = __builtin_bit_cast(unsigned, f);
    u += 0x7fffu + ((u >> 16) & 1u);
    return (unsigned short)(u >> 16);
}
__device__ __forceinline__ float bf2f(unsigned short b) {
    unsigned u = ((unsigned)b) << 16;
    return __builtin_bit_cast(float, u);
}
__device__ __forceinline__ unsigned swz3(int key) { return (unsigned)((key ^ (key >> 3)) & 7); }
__device__ __forceinline__ bf16x8 ldfrag(const char* p) { return __builtin_bit_cast(bf16x8, *(const u32x4*)p); }
__device__ __forceinline__ bf16x8 castf(u32x4 v) { return __builtin_bit_cast(bf16x8, v); }

// ---------------------------------------------------------------------------
// prep: pack W into MFMA A-fragment layout (bf16).
// frag element (kk, nt, lane, e) = W[f][h]:
//   f = kk*16 + (lane>>5)*8 + e + (nt>=2 ? F : 0)   (nt>=2 -> Wbot)
//   h = (nt&1)*32 + (lane&31)
// Flat: wpk[base + ((kk*4+nt)*64 + lane)*8 + e].
// Bases (elems): L0 @0 (2048), L1 @2048, L2 @18432, L3 @34816 (16384 each).
__global__ __launch_bounds__(256)
void prep(const float* __restrict__ W0, const float* __restrict__ W1,
          const float* __restrict__ W2, const float* __restrict__ W3,
          unsigned short* __restrict__ wpk)
{
    int id = blockIdx.x * 256 + threadIdx.x;
    if (id >= 51200) return;
    float v;
    if (id < 2048) {
        int j = id;
        int e = j & 7, lane = (j >> 3) & 63, nt = (j >> 9) & 3;
        int f = ((lane >> 5) << 3) + e + ((nt >= 2) ? 16 : 0);
        int h = ((nt & 1) << 5) + (lane & 31);
        v = W0[f * 64 + h];
    } else {
        int jid = id - 2048;
        int l = jid >> 14;            // 0,1,2 -> layers 1,2,3
        int j = jid & 16383;
        int e = j & 7, lane = (j >> 3) & 63, nt = (j >> 9) & 3, kk = j >> 11;
        int f = kk * 16 + ((lane >> 5) << 3) + e + ((nt >= 2) ? 128 : 0);
        int h = ((nt & 1) << 5) + (lane & 31);
        const float* W = (l == 0) ? W1 : (l == 1) ? W2 : W3;
        int H = (l == 2) ? 4 : 64;
        v = (h < H) ? W[f * H + h] : 0.f;
    }
    wpk[id] = f2bf(v);
}

// ---------------------------------------------------------------------------
// tgen: P[b][i][j] = round_bf16( round_bf16(exp(exp(-d*p))) / rowsum ).
// sc SKEWED (idx = k + (k>>3)); tile rows XOR-swizzled by (r&7)<<4.
__global__ __launch_bounds__(256, 3)
void tgen(const float* __restrict__ coords, const float* __restrict__ psq,
          unsigned short* __restrict__ Tg, float* __restrict__ pcol)
{
    __shared__ float4 sc[1152];          // skewed coords+norm
    __shared__ char   tile[16 * 2048];   // [16 r][1024 j] bf16, row-swizzled
    const int t = threadIdx.x;
    const int b = blockIdx.y;
    const int i0 = blockIdx.x * 16;
    for (int k = t; k < 1024; k += 256) {
        const float* c = coords + ((size_t)b*1024 + k)*3;
        float cx = c[0], cy = c[1], cz = c[2];
        sc[k + (k >> 3)] = make_float4(cx, cy, cz, cx*cx + cy*cy + cz*cz);
    }
    __syncthreads();
    const float p = psq[0];
    const int r = t >> 4, jg = t & 15;
    const int kci = i0 + r;
    const float4 ci = sc[kci + (kci >> 3)];
    const unsigned rsw = (unsigned)(r & 7) << 4;
    u32x4 raw[8];
    float rsum = 0.f;
#pragma unroll
    for (int pp = 0; pp < 8; ++pp) {
        const int base = pp*144 + jg*9;   // skewed index of j = pp*128 + jg*8
        u32x4 v;
#pragma unroll
        for (int e = 0; e < 4; ++e) {
            float4 cj0 = sc[base + 2*e], cj1 = sc[base + 2*e + 1];
            float d0 = ci.w + cj0.w - 2.f*(ci.x*cj0.x + ci.y*cj0.y + ci.z*cj0.z);
            float d1 = ci.w + cj1.w - 2.f*(ci.x*cj1.x + ci.y*cj1.y + ci.z*cj1.z);
            unsigned short h0 = f2bf(__expf(__expf(-d0 * p)));
            unsigned short h1 = f2bf(__expf(__expf(-d1 * p)));
            rsum += bf2f(h0) + bf2f(h1);
            v[e] = (unsigned)h0 | ((unsigned)h1 << 16);
        }
        raw[pp] = v;
    }
    rsum += __shfl_xor(rsum, 1);
    rsum += __shfl_xor(rsum, 2);
    rsum += __shfl_xor(rsum, 4);
    rsum += __shfl_xor(rsum, 8);
    const float rinv = 1.f / rsum;
    char* trow = tile + r * 2048;
#pragma unroll
    for (int pp = 0; pp < 8; ++pp) {
        u32x4 u = raw[pp], v;
#pragma unroll
        for (int e = 0; e < 4; ++e) {
            unsigned uu = u[e];
            unsigned short nl = f2bf(bf2f((unsigned short)(uu & 0xffffu)) * rinv);
            unsigned short nh = f2bf(bf2f((unsigned short)(uu >> 16)) * rinv);
            v[e] = (unsigned)nl | ((unsigned)nh << 16);
        }
        *(u32x4*)(trow + (((unsigned)(pp*256 + jg*16)) ^ rsw)) = v;
    }
    __syncthreads();
    {   // column-sum partial over the 16 rows
        f32x4 cs = {0.f, 0.f, 0.f, 0.f};
#pragma unroll
        for (int rr = 0; rr < 16; ++rr) {
            u32x2 u = *(const u32x2*)(tile + rr*2048 + (((unsigned)(t*8)) ^ ((unsigned)(rr & 7) << 4)));
            cs[0] += bf2f((unsigned short)(u[0] & 0xffffu));
            cs[1] += bf2f((unsigned short)(u[0] >> 16));
            cs[2] += bf2f((unsigned short)(u[1] & 0xffffu));
            cs[3] += bf2f((unsigned short)(u[1] >> 16));
        }
        *(f32x4*)(pcol + ((size_t)(b*64 + blockIdx.x))*1024 + t*4) = cs;
    }
    {   // flat coalesced store (un-swizzling reads)
        u32x4* dst = (u32x4*)(Tg + ((size_t)(b*1024 + i0))*1024);
        for (int v = t; v < 2048; v += 256) {
            const int row = v >> 7;
            const unsigned cin = ((unsigned)((v & 127) * 16)) ^ ((unsigned)(row & 7) << 4);
            dst[v] = *(const u32x4*)(tile + row*2048 + cin);
        }
    }
}

// ---------------------------------------------------------------------------
// proj0: v/u = bf16(x) @ W0top / W0bot (+b0 on u). Emits vuT [b][128 h][1024 i].
__global__ __launch_bounds__(256, 2)
void proj0(const float* __restrict__ x32, const unsigned short* __restrict__ wpk,
           const float* __restrict__ bias, unsigned short* __restrict__ vuT)
{
    __shared__ char smem[2048 + 4096 + 16384];
    constexpr int XS = 0, WS = 2048, TBO = 6144;
    const int t = threadIdx.x;
    const int l = t & 63, w = t >> 6;
    const int b = blockIdx.y;
    const int i0g = blockIdx.x * 64;
    const int m31 = l & 31, kg = l >> 5;
    const int mi = w & 1, ntb = (w >> 1) * 2;
    const float bv = bias[0];

    {   // stage x tile [64 i][16 f] bf16
        const int i = t >> 2, q = t & 3;
        const float* s = x32 + ((size_t)(b*1024 + i0g + i))*16 + q*4;
        unsigned short h0 = f2bf(s[0]), h1 = f2bf(s[1]), h2 = f2bf(s[2]), h3 = f2bf(s[3]);
        u32x2 v = {(unsigned)h0 | ((unsigned)h1 << 16), (unsigned)h2 | ((unsigned)h3 << 16)};
        *(u32x2*)(smem + XS + i*32 + ((q*8) ^ ((i & 1) << 4))) = v;
    }
    {   // stage packed W0 (linear)
        u32x4* dstw = (u32x4*)(smem + WS);
        const u32x4* srcw = (const u32x4*)wpk;
        if (t < 256) dstw[t] = srcw[t];
    }
    __syncthreads();

    f32x16 acc0, acc1;
#pragma unroll
    for (int r = 0; r < 16; ++r) { acc0[r] = 0.f; acc1[r] = 0.f; }
    const int arow = mi*32 + m31;
    const char* ap = smem + XS + arow * 32;
    const unsigned swA = (unsigned)(arow & 1) << 4;
    {
        bf16x8 a  = ldfrag(ap + ((kg*16) ^ swA));
        bf16x8 b0 = ldfrag(smem + WS + (ntb    )*1024 + l*16);
        bf16x8 b1 = ldfrag(smem + WS + (ntb + 1)*1024 + l*16);
        acc0 = __builtin_amdgcn_mfma_f32_32x32x16_bf16(a, b0, acc0, 0, 0, 0);
        acc1 = __builtin_amdgcn_mfma_f32_32x32x16_bf16(a, b1, acc1, 0, 0, 0);
    }
    __syncthreads();
#pragma unroll
    for (int ntp = 0; ntp < 2; ++ntp) {
        const int nt = ntb + ntp;
        const int prow = nt*32 + m31;
        char* tb = smem + TBO + prow*128;
        const unsigned sw = (unsigned)(prow & 7) << 4;
        const float badd = (nt >= 2) ? bv : 0.f;
#pragma unroll
        for (int r = 0; r < 16; ++r) {
            const int i = mi*32 + (r & 3) + 8*(r >> 2) + 4*kg;
            float z = ((ntp == 0) ? acc0[r] : acc1[r]) + badd;
            *(unsigned short*)(tb + ((i*2) ^ sw)) = f2bf(z);
        }
    }
    __syncthreads();
    {
        const int hh = t >> 1, q = t & 1;
        const char* tb = smem + TBO + hh*128;
        const unsigned sw = (unsigned)(hh & 7) << 4;
        unsigned short* g = vuT + ((size_t)(b*128 + hh))*1024 + i0g + q*32;
#pragma unroll
        for (int gg = 0; gg < 4; ++gg) {
            u32x4 v = *(const u32x4*)(tb + ((q*64 + gg*16) ^ sw));
            *(u32x4*)(g + gg*8) = v;
        }
    }
}

// ---------------------------------------------------------------------------
// fspmm: z = P @ v + u; BN; x' = concat(z', relu z'); fused next projection.
// Main loop is BARRIER-FREE: A/B MFMA fragments loaded directly from global
// (P and vuT are row-major planes whose rows ARE the fragment rows).
__global__ __launch_bounds__(256, 2)
void fspmm(const unsigned short* __restrict__ vuT, const unsigned short* __restrict__ P,
           const float* __restrict__ gamma, const float* __restrict__ beta,
           const unsigned short* __restrict__ wpkN, const float* __restrict__ biasN,
           unsigned short* __restrict__ ovuT)
{
    __shared__ char ZT[16384];   // epilogue concat buffer; reused as transpose buf
    const int t = threadIdx.x;
    const int l = t & 63, w = t >> 6;
    const int b = blockIdx.y;
    const int i0g = blockIdx.x * 64;
    const int m31 = l & 31, kg = l >> 5;
    const int wh = w >> 1, wi2 = w & 1;
    const float bvN = biasN[0];

    // fragment base pointers: lane l reads row (l&31) of its operand plane
    const unsigned short* gA = vuT + ((size_t)(b*128  + wh*32  + m31))*1024 + kg*8;  // v[h][j]
    const unsigned short* gB = P   + ((size_t)(b*1024 + i0g + wi2*32 + m31))*1024 + kg*8;  // P[i][j]

    f32x16 acc;
#pragma unroll
    for (int r = 0; r < 16; ++r) acc[r] = 0.f;

    u32x4 Xa0, Xa1, Xa2, Xa3, Xb0, Xb1, Xb2, Xb3;
    u32x4 Ya0, Ya1, Ya2, Ya3, Yb0, Yb1, Yb2, Yb3;

#define LD8(Sa0,Sa1,Sa2,Sa3,Sb0,Sb1,Sb2,Sb3, JT) do {                      \
        const unsigned short* pa_ = gA + (JT)*64;                          \
        const unsigned short* pb_ = gB + (JT)*64;                          \
        Sa0 = *(const u32x4*)(pa_);      Sa1 = *(const u32x4*)(pa_ + 16);  \
        Sa2 = *(const u32x4*)(pa_ + 32); Sa3 = *(const u32x4*)(pa_ + 48);  \
        Sb0 = *(const u32x4*)(pb_);      Sb1 = *(const u32x4*)(pb_ + 16);  \
        Sb2 = *(const u32x4*)(pb_ + 32); Sb3 = *(const u32x4*)(pb_ + 48);  \
    } while (0)
#define MM4(Sa0,Sa1,Sa2,Sa3,Sb0,Sb1,Sb2,Sb3) do {                                   \
        acc = __builtin_amdgcn_mfma_f32_32x32x16_bf16(castf(Sa0), castf(Sb0), acc, 0, 0, 0); \
        acc = __builtin_amdgcn_mfma_f32_32x32x16_bf16(castf(Sa1), castf(Sb1), acc, 0, 0, 0); \
        acc = __builtin_amdgcn_mfma_f32_32x32x16_bf16(castf(Sa2), castf(Sb2), acc, 0, 0, 0); \
        acc = __builtin_amdgcn_mfma_f32_32x32x16_bf16(castf(Sa3), castf(Sb3), acc, 0, 0, 0); \
    } while (0)

    LD8(Xa0,Xa1,Xa2,Xa3,Xb0,Xb1,Xb2,Xb3, 0);
#pragma unroll
    for (int jt = 0; jt < 16; jt += 2) {
        LD8(Ya0,Ya1,Ya2,Ya3,Yb0,Yb1,Yb2,Yb3, jt + 1);
        MM4(Xa0,Xa1,Xa2,Xa3,Xb0,Xb1,Xb2,Xb3);
        if (jt + 2 < 16) LD8(Xa0,Xa1,Xa2,Xa3,Xb0,Xb1,Xb2,Xb3, jt + 2);
        MM4(Ya0,Ya1,Ya2,Ya3,Yb0,Yb1,Yb2,Yb3);
    }
#undef LD8
#undef MM4

    // ---- epilogue: z = acc + u, BN, concat into ZT [64 i][256 B] swizzled ----
    const float bns = rsqrtf(1.f + 1e-3f);
    const int ii = wi2*32 + m31;
    const unsigned swzi = (unsigned)(ii & 7) << 4;
    const unsigned short* gu = vuT + ((size_t)(b*128 + 64))*1024 + i0g + ii;
#pragma unroll
    for (int r = 0; r < 16; ++r) {
        const int h = wh*32 + (r & 3) + 8*(r >> 2) + 4*kg;
        float u = bf2f(gu[(size_t)h * 1024]);
        float z = (acc[r] + u) * (gamma[h] * bns) + beta[h];
        *(unsigned short*)(ZT + ii*256 + (((unsigned)(h*2)) ^ swzi))        = f2bf(z);
        *(unsigned short*)(ZT + ii*256 + (((unsigned)((64 + h)*2)) ^ swzi)) = f2bf(fmaxf(z, 0.f));
    }
    __syncthreads();

    // ---- fused next-layer projection: A = W' frags (global), B = x' (ZT) ----
    f32x16 vac, uac;
#pragma unroll
    for (int r = 0; r < 16; ++r) { vac[r] = 0.f; uac[r] = bvN; }
    const char* bx_base = ZT + ii*256;
#pragma unroll
    for (int kk = 0; kk < 8; ++kk) {
        bf16x8 awv = __builtin_bit_cast(bf16x8, *(const u32x4*)(wpkN + ((size_t)((kk*4 + wh    )*64 + l))*8));
        bf16x8 awu = __builtin_bit_cast(bf16x8, *(const u32x4*)(wpkN + ((size_t)((kk*4 + wh + 2)*64 + l))*8));
        bf16x8 bx  = ldfrag(bx_base + ((kk*32 + kg*16) ^ swzi));
        vac = __builtin_amdgcn_mfma_f32_32x32x16_bf16(awv, bx, vac, 0, 0, 0);
        uac = __builtin_amdgcn_mfma_f32_32x32x16_bf16(awu, bx, uac, 0, 0, 0);
    }
    __syncthreads();
    {   // transpose into ZT reused as TB [128 h'][128 B]
#pragma unroll
        for (int r = 0; r < 16; ++r) {
            const int hv = wh*32 + (r & 3) + 8*(r >> 2) + 4*kg;
            const unsigned sw = (unsigned)(hv & 7) << 4;
            *(unsigned short*)(ZT + hv*128        + ((ii*2) ^ sw)) = f2bf(vac[r]);
            *(unsigned short*)(ZT + (hv + 64)*128 + ((ii*2) ^ sw)) = f2bf(uac[r]);
        }
    }
    __syncthreads();
    {
        const int hh = t >> 1, q = t & 1;
        const char* tb = ZT + hh*128;
        const unsigned sw = (unsigned)(hh & 7) << 4;
        unsigned short* g = ovuT + ((size_t)(b*128 + hh))*1024 + i0g + q*32;
#pragma unroll
        for (int gg = 0; gg < 4; ++gg) {
            u32x4 v = *(const u32x4*)(tb + ((q*64 + gg*16) ^ sw));
            *(u32x4*)(g + gg*8) = v;
        }
    }
}

// ---------------------------------------------------------------------------
// finalize: logits[h] = ( colsum(P)·v3 + sum_i u3 ) / 1024; out = softmax.
__global__ __launch_bounds__(256)
void finalize(const float* __restrict__ pcol, const unsigned short* __restrict__ vuT3,
              float* __restrict__ out)
{
    __shared__ float red[2056];
    const int b = blockIdx.x, t = threadIdx.x;
    const int j0 = t * 4;
    f32x4 cs = {0.f, 0.f, 0.f, 0.f};
    for (int p = 0; p < 64; ++p)
        cs += *(const f32x4*)(pcol + ((size_t)(b*64 + p))*1024 + j0);
    float lv[4], lu[4];
#pragma unroll
    for (int h = 0; h < 4; ++h) {
        const unsigned short* vr = vuT3 + ((size_t)(b*128 + h))*1024 + j0;
        lv[h] = cs[0]*bf2f(vr[0]) + cs[1]*bf2f(vr[1]) + cs[2]*bf2f(vr[2]) + cs[3]*bf2f(vr[3]);
        const unsigned short* ur = vuT3 + ((size_t)(b*128 + 64 + h))*1024 + j0;
        lu[h] = bf2f(ur[0]) + bf2f(ur[1]) + bf2f(ur[2]) + bf2f(ur[3]);
    }
#pragma unroll
    for (int q = 0; q < 4; ++q) { red[t*8 + q] = lv[q]; red[t*8 + 4 + q] = lu[q]; }
    __syncthreads();
    if (t < 8) {
        float s = 0.f;
        for (int k = 0; k < 256; ++k) s += red[k*8 + t];
        red[2048 + t] = s;
    }
    __syncthreads();
    if (t == 0) {
        float v[4];
#pragma unroll
        for (int h = 0; h < 4; ++h) v[h] = (red[2048 + h] + red[2048 + 4 + h]) * (1.f / 1024.f);
        const float m = fmaxf(fmaxf(v[0], v[1]), fmaxf(v[2], v[3]));
        float e[4], se = 0.f;
#pragma unroll
        for (int h = 0; h < 4; ++h) { e[h] = __expf(v[h] - m); se += e[h]; }
        const float inv = 1.f / se;
#pragma unroll
        for (int h = 0; h < 4; ++h) out[b*4 + h] = e[h] * inv;
    }
}

extern "C" void kernel_launch(void* const* d_in, const int* in_sizes, int n_in,
                              void* d_out, int out_size, void* d_ws, size_t ws_size,
                              hipStream_t stream)
{
    const float* x   = (const float*)d_in[0];
    const float* co  = (const float*)d_in[1];
    const float* psq = (const float*)d_in[2];
    const float* W0  = (const float*)d_in[3];
    const float* W1  = (const float*)d_in[4];
    const float* W2  = (const float*)d_in[5];
    const float* W3  = (const float*)d_in[6];
    const float* b0  = (const float*)d_in[7];
    const float* b1  = (const float*)d_in[8];
    const float* b2  = (const float*)d_in[9];
    const float* b3  = (const float*)d_in[10];
    const float* g0  = (const float*)d_in[11];
    const float* be0 = (const float*)d_in[12];
    const float* g1  = (const float*)d_in[13];
    const float* be1 = (const float*)d_in[14];
    const float* g2  = (const float*)d_in[15];
    const float* be2 = (const float*)d_in[16];

    char* ws = (char*)d_ws;
    const size_t MB = (size_t)1 << 20;
    unsigned short* P    = (unsigned short*)(ws);             // 64 MB
    float*          pcol = (float*)(ws + 64*MB);              // 8 MB
    unsigned short* vuA  = (unsigned short*)(ws + 72*MB);     // 8 MB
    unsigned short* vuB  = (unsigned short*)(ws + 80*MB);     // 8 MB
    unsigned short* wpk  = (unsigned short*)(ws + 88*MB);     // 100 KB

    prep<<<dim3(200), 256, 0, stream>>>(W0, W1, W2, W3, wpk);
    tgen<<<dim3(64, 32), 256, 0, stream>>>(co, psq, P, pcol);

    dim3 grid(16, 32);
    proj0<<<grid, 256, 0, stream>>>(x, wpk, b0, vuA);
    fspmm<<<grid, 256, 0, stream>>>(vuA, P, g0, be0, wpk + 2048,  b1, vuB);
    fspmm<<<grid, 256, 0, stream>>>(vuB, P, g1, be1, wpk + 18432, b2, vuA);
    fspmm<<<grid, 256, 0, stream>>>(vuA, P, g2, be2, wpk + 34816, b3, vuB);
    finalize<<<dim3(32), 256, 0, stream>>>(pcol, vuB, (float*)d_out);
}

// Round 9
// 189.899 us; speedup vs baseline: 1.2598x; 1.2598x over previous
//
#include <hip/hip_runtime.h>
#include <math.h>

typedef __attribute__((ext_vector_type(8)))  __bf16   bf16x8;
typedef __attribute__((ext_vector_type(4)))  float    f32x4;
typedef __attribute__((ext_vector_type(16))) float    f32x16;
typedef __attribute__((ext_vector_type(4)))  unsigned u32x4;
typedef __attribute__((ext_vector_type(2)))  unsigned u32x2;

__device__ __forceinline__ unsigned short f2bf(float f) {
    unsigned u = __builtin_bit_cast(unsigned, f);
    u += 0x7fffu + ((u >> 16) & 1u);
    return (unsigned short)(u >> 16);
}
__device__ __forceinline__ float bf2f(unsigned short b) {
    unsigned u = ((unsigned)b) << 16;
    return __builtin_bit_cast(float, u);
}
__device__ __forceinline__ unsigned swz3(int key) { return (unsigned)((key ^ (key >> 3)) & 7); }
__device__ __forceinline__ bf16x8 ldfrag(const char* p) { return __builtin_bit_cast(bf16x8, *(const u32x4*)p); }

typedef __attribute__((address_space(1))) unsigned int gu32;
typedef __attribute__((address_space(3))) unsigned int lu32;
__device__ __forceinline__ void gl_lds16(const void* g, void* l) {
    __builtin_amdgcn_global_load_lds((gu32*)g, (lu32*)l, 16, 0, 0);
}

// ---------------------------------------------------------------------------
// prep: pack W into MFMA A-fragment layout (bf16).
// frag element (kk, nt, lane, e) = W[f][h]:
//   f = kk*16 + (lane>>5)*8 + e + (nt>=2 ? F : 0)   (nt>=2 -> Wbot)
//   h = (nt&1)*32 + (lane&31)
// Flat: wpk[base + ((kk*4+nt)*64 + lane)*8 + e].
// Bases (elems): L0 @0 (2048), L1 @2048, L2 @18432, L3 @34816 (16384 each).
__global__ __launch_bounds__(256)
void prep(const float* __restrict__ W0, const float* __restrict__ W1,
          const float* __restrict__ W2, const float* __restrict__ W3,
          unsigned short* __restrict__ wpk)
{
    int id = blockIdx.x * 256 + threadIdx.x;
    if (id >= 51200) return;
    float v;
    if (id < 2048) {
        int j = id;
        int e = j & 7, lane = (j >> 3) & 63, nt = (j >> 9) & 3;
        int f = ((lane >> 5) << 3) + e + ((nt >= 2) ? 16 : 0);
        int h = ((nt & 1) << 5) + (lane & 31);
        v = W0[f * 64 + h];
    } else {
        int jid = id - 2048;
        int l = jid >> 14;            // 0,1,2 -> layers 1,2,3
        int j = jid & 16383;
        int e = j & 7, lane = (j >> 3) & 63, nt = (j >> 9) & 3, kk = j >> 11;
        int f = kk * 16 + ((lane >> 5) << 3) + e + ((nt >= 2) ? 128 : 0);
        int h = ((nt & 1) << 5) + (lane & 31);
        const float* W = (l == 0) ? W1 : (l == 1) ? W2 : W3;
        int H = (l == 2) ? 4 : 64;
        v = (h < H) ? W[f * H + h] : 0.f;
    }
    wpk[id] = f2bf(v);
}

// ---------------------------------------------------------------------------
// tgen: P[b][i][j] = round_bf16( round_bf16(exp(exp(-d*p))) / rowsum ).
// sc is SKEWED (idx = k + (k>>3)) so the jg*8-strided reads are conflict-free.
__global__ __launch_bounds__(256, 3)
void tgen(const float* __restrict__ coords, const float* __restrict__ psq,
          unsigned short* __restrict__ Tg, float* __restrict__ pcol)
{
    __shared__ float4 sc[1152];          // skewed coords+norm
    __shared__ char   tile[16 * 2048];   // [16 r][1024 j] bf16
    const int t = threadIdx.x;
    const int b = blockIdx.y;
    const int i0 = blockIdx.x * 16;
    for (int k = t; k < 1024; k += 256) {
        const float* c = coords + ((size_t)b*1024 + k)*3;
        float cx = c[0], cy = c[1], cz = c[2];
        sc[k + (k >> 3)] = make_float4(cx, cy, cz, cx*cx + cy*cy + cz*cz);
    }
    __syncthreads();
    const float p = psq[0];
    const int r = t >> 4, jg = t & 15;
    const int kci = i0 + r;
    const float4 ci = sc[kci + (kci >> 3)];
    u32x4 raw[8];
    float rsum = 0.f;
#pragma unroll
    for (int pp = 0; pp < 8; ++pp) {
        const int base = pp*144 + jg*9;   // skewed index of j = pp*128 + jg*8
        u32x4 v;
#pragma unroll
        for (int e = 0; e < 4; ++e) {
            float4 cj0 = sc[base + 2*e], cj1 = sc[base + 2*e + 1];
            float d0 = ci.w + cj0.w - 2.f*(ci.x*cj0.x + ci.y*cj0.y + ci.z*cj0.z);
            float d1 = ci.w + cj1.w - 2.f*(ci.x*cj1.x + ci.y*cj1.y + ci.z*cj1.z);
            unsigned short h0 = f2bf(__expf(__expf(-d0 * p)));
            unsigned short h1 = f2bf(__expf(__expf(-d1 * p)));
            rsum += bf2f(h0) + bf2f(h1);
            v[e] = (unsigned)h0 | ((unsigned)h1 << 16);
        }
        raw[pp] = v;
    }
    rsum += __shfl_xor(rsum, 1);
    rsum += __shfl_xor(rsum, 2);
    rsum += __shfl_xor(rsum, 4);
    rsum += __shfl_xor(rsum, 8);
    const float rinv = 1.f / rsum;
    char* trow = tile + r * 2048;
#pragma unroll
    for (int pp = 0; pp < 8; ++pp) {
        u32x4 u = raw[pp], v;
#pragma unroll
        for (int e = 0; e < 4; ++e) {
            unsigned uu = u[e];
            unsigned short nl = f2bf(bf2f((unsigned short)(uu & 0xffffu)) * rinv);
            unsigned short nh = f2bf(bf2f((unsigned short)(uu >> 16)) * rinv);
            v[e] = (unsigned)nl | ((unsigned)nh << 16);
        }
        *(u32x4*)(trow + (pp*128 + jg*8)*2) = v;
    }
    __syncthreads();
    {   // column-sum partial over the 16 rows
        const int j0 = t * 4;
        f32x4 cs = {0.f, 0.f, 0.f, 0.f};
#pragma unroll
        for (int rr = 0; rr < 16; ++rr) {
            u32x2 u = *(const u32x2*)(tile + rr*2048 + j0*2);
            cs[0] += bf2f((unsigned short)(u[0] & 0xffffu));
            cs[1] += bf2f((unsigned short)(u[0] >> 16));
            cs[2] += bf2f((unsigned short)(u[1] & 0xffffu));
            cs[3] += bf2f((unsigned short)(u[1] >> 16));
        }
        *(f32x4*)(pcol + ((size_t)(b*64 + blockIdx.x))*1024 + j0) = cs;
    }
    {   // flat coalesced store: rows i0..i0+15 are contiguous in Tg
        const u32x4* src = (const u32x4*)tile;
        u32x4* dst = (u32x4*)(Tg + ((size_t)(b*1024 + i0))*1024);
        for (int v = t; v < 2048; v += 256) dst[v] = src[v];
    }
}

// ---------------------------------------------------------------------------
// proj0: v/u = bf16(x) @ W0top / W0bot (+b0 on u). Emits vuT [b][128 h][1024 i].
__global__ __launch_bounds__(256, 2)
void proj0(const float* __restrict__ x32, const unsigned short* __restrict__ wpk,
           const float* __restrict__ bias, unsigned short* __restrict__ vuT)
{
    __shared__ char smem[2048 + 4096 + 16384];
    constexpr int XS = 0, WS = 2048, TBO = 6144;
    const int t = threadIdx.x;
    const int l = t & 63, w = t >> 6;
    const int b = blockIdx.y;
    const int i0g = blockIdx.x * 64;
    const int m31 = l & 31, kg = l >> 5;
    const int mi = w & 1, ntb = (w >> 1) * 2;
    const float bv = bias[0];

    {   // stage x tile [64 i][16 f] bf16
        const int i = t >> 2, q = t & 3;
        const float* s = x32 + ((size_t)(b*1024 + i0g + i))*16 + q*4;
        unsigned short h0 = f2bf(s[0]), h1 = f2bf(s[1]), h2 = f2bf(s[2]), h3 = f2bf(s[3]);
        u32x2 v = {(unsigned)h0 | ((unsigned)h1 << 16), (unsigned)h2 | ((unsigned)h3 << 16)};
        *(u32x2*)(smem + XS + i*32 + ((q*8) ^ ((i & 1) << 4))) = v;
    }
    {   // stage packed W0 (linear)
        u32x4* dstw = (u32x4*)(smem + WS);
        const u32x4* srcw = (const u32x4*)wpk;
        if (t < 256) dstw[t] = srcw[t];
    }
    __syncthreads();

    f32x16 acc0, acc1;
#pragma unroll
    for (int r = 0; r < 16; ++r) { acc0[r] = 0.f; acc1[r] = 0.f; }
    const int arow = mi*32 + m31;
    const char* ap = smem + XS + arow * 32;
    const unsigned swA = (unsigned)(arow & 1) << 4;
    {
        bf16x8 a  = ldfrag(ap + ((kg*16) ^ swA));
        bf16x8 b0 = ldfrag(smem + WS + (ntb    )*1024 + l*16);
        bf16x8 b1 = ldfrag(smem + WS + (ntb + 1)*1024 + l*16);
        acc0 = __builtin_amdgcn_mfma_f32_32x32x16_bf16(a, b0, acc0, 0, 0, 0);
        acc1 = __builtin_amdgcn_mfma_f32_32x32x16_bf16(a, b1, acc1, 0, 0, 0);
    }
    __syncthreads();
#pragma unroll
    for (int ntp = 0; ntp < 2; ++ntp) {
        const int nt = ntb + ntp;
        const int prow = nt*32 + m31;
        char* tb = smem + TBO + prow*128;
        const unsigned sw = (unsigned)(prow & 7) << 4;
        const float badd = (nt >= 2) ? bv : 0.f;
#pragma unroll
        for (int r = 0; r < 16; ++r) {
            const int i = mi*32 + (r & 3) + 8*(r >> 2) + 4*kg;
            float z = ((ntp == 0) ? acc0[r] : acc1[r]) + badd;
            *(unsigned short*)(tb + ((i*2) ^ sw)) = f2bf(z);
        }
    }
    __syncthreads();
    {
        const int hh = t >> 1, q = t & 1;
        const char* tb = smem + TBO + hh*128;
        const unsigned sw = (unsigned)(hh & 7) << 4;
        unsigned short* g = vuT + ((size_t)(b*128 + hh))*1024 + i0g + q*32;
#pragma unroll
        for (int gg = 0; gg < 4; ++gg) {
            u32x4 v = *(const u32x4*)(tb + ((q*64 + gg*16) ^ sw));
            *(u32x4*)(g + gg*8) = v;
        }
    }
}

// ---------------------------------------------------------------------------
// fspmm: z = P @ v + u; BN; x' = concat(z', relu z'); fused next projection.
// Staging via global_load_lds (16B), LDS dest linear, swizzle pre-applied to
// the GLOBAL source address (read side identical to reg-staged version).
__global__ __launch_bounds__(256, 2)
void fspmm(const unsigned short* __restrict__ vuT, const unsigned short* __restrict__ P,
           const float* __restrict__ gamma, const float* __restrict__ beta,
           const unsigned short* __restrict__ wpkN, const float* __restrict__ biasN,
           unsigned short* __restrict__ ovuT)
{
    __shared__ char smem[32768];   // PT dbuf [2][8K] @0; VT dbuf [2][8K] @16K
    const int t = threadIdx.x;
    const int l = t & 63, w = t >> 6;
    const int b = blockIdx.y;
    const int i0g = blockIdx.x * 64;
    const int m31 = l & 31, kg = l >> 5;
    const int wh = w >> 1, wi2 = w & 1;
    const float bvN = biasN[0];

    // staging geometry: thread (w, l) transfers chunk (l&7) of rows
    // r0 = w*16 + (l>>3) and r1 = r0 + 8  (LDS linear: row*128 + chunk*16).
    const int r0 = w*16 + (l >> 3);
    const int r1 = r0 + 8;
    const int c  = l & 7;
    const unsigned so0 = ((unsigned)(c*16)) ^ (swz3(r0) << 4);
    const unsigned so1 = ((unsigned)(c*16)) ^ (swz3(r1) << 4);
    const char* gp0 = (const char*)(P   + ((size_t)(b*1024 + i0g + r0))*1024) + so0;
    const char* gp1 = (const char*)(P   + ((size_t)(b*1024 + i0g + r1))*1024) + so1;
    const char* gv0 = (const char*)(vuT + ((size_t)(b*128 + r0))*1024) + so0;
    const char* gv1 = (const char*)(vuT + ((size_t)(b*128 + r1))*1024) + so1;

    const int aRow = wh*32 + m31, bRow = wi2*32 + m31;
    const unsigned swA = swz3(aRow) << 4, swB = swz3(bRow) << 4;

    f32x16 acc;
#pragma unroll
    for (int r = 0; r < 16; ++r) acc[r] = 0.f;

    {   // prologue: tile 0 -> buf 0
        char* pb = smem + w*2048;
        char* vb = smem + 16384 + w*2048;
        gl_lds16(gp0, pb);
        gl_lds16(gp1, pb + 1024);
        gl_lds16(gv0, vb);
        gl_lds16(gv1, vb + 1024);
    }
    __syncthreads();

    for (int jt = 0; jt < 16; ++jt) {
        const int p = jt & 1;
        if (jt < 15) {   // issue next tile into buf p^1 (drains at the barrier)
            const int off = (jt + 1) * 128;
            char* pb = smem + (p^1)*8192 + w*2048;
            char* vb = smem + 16384 + (p^1)*8192 + w*2048;
            gl_lds16(gp0 + off, pb);
            gl_lds16(gp1 + off, pb + 1024);
            gl_lds16(gv0 + off, vb);
            gl_lds16(gv1 + off, vb + 1024);
        }
        const char* a_ = smem + 16384 + p*8192 + aRow*128;
        const char* b_ = smem + p*8192 + bRow*128;
#pragma unroll
        for (int kk = 0; kk < 4; ++kk) {
            const unsigned off = kk*32 + kg*16;
            bf16x8 af = ldfrag(a_ + (off ^ swA));
            bf16x8 bf = ldfrag(b_ + (off ^ swB));
            acc = __builtin_amdgcn_mfma_f32_32x32x16_bf16(af, bf, acc, 0, 0, 0);
        }
        __syncthreads();
    }

    // ---- epilogue: z, BN, x' tile ----
    {   // stage u tile [64 h][64 i] linear @0
        const int r4 = t >> 2, c4 = t & 3;
        const unsigned short* gu = vuT + ((size_t)(b*128 + 64 + r4))*1024 + i0g + c4*16;
        u32x4 u0 = *(const u32x4*)(gu), u1 = *(const u32x4*)(gu + 8);
        *(u32x4*)(smem + r4*128 + c4*32)      = u0;
        *(u32x4*)(smem + r4*128 + c4*32 + 16) = u1;
    }
    __syncthreads();
    const float bns = rsqrtf(1.f + 1e-3f);
    const int ii = wi2*32 + m31;
    char* ZT = smem + 16384;     // [64 i][256 B] bf16, swizzled by (i&7)
    const unsigned swzi = (unsigned)(ii & 7) << 4;
#pragma unroll
    for (int r = 0; r < 16; ++r) {
        const int h = wh*32 + (r & 3) + 8*(r >> 2) + 4*kg;
        float u = bf2f(*(const unsigned short*)(smem + h*128 + ii*2));
        float z = (acc[r] + u) * (gamma[h] * bns) + beta[h];
        *(unsigned short*)(ZT + ii*256 + (((unsigned)(h*2)) ^ swzi))        = f2bf(z);
        *(unsigned short*)(ZT + ii*256 + (((unsigned)((64 + h)*2)) ^ swzi)) = f2bf(fmaxf(z, 0.f));
    }
    __syncthreads();

    // ---- fused next-layer projection: A = W' frags (global), B = x' (ZT) ----
    f32x16 vac, uac;
#pragma unroll
    for (int r = 0; r < 16; ++r) { vac[r] = 0.f; uac[r] = bvN; }
    const char* bx_base = ZT + ii*256;
#pragma unroll
    for (int kk = 0; kk < 8; ++kk) {
        bf16x8 awv = __builtin_bit_cast(bf16x8, *(const u32x4*)(wpkN + ((size_t)((kk*4 + wh    )*64 + l))*8));
        bf16x8 awu = __builtin_bit_cast(bf16x8, *(const u32x4*)(wpkN + ((size_t)((kk*4 + wh + 2)*64 + l))*8));
        bf16x8 bx  = ldfrag(bx_base + ((kk*32 + kg*16) ^ swzi));
        vac = __builtin_amdgcn_mfma_f32_32x32x16_bf16(awv, bx, vac, 0, 0, 0);
        uac = __builtin_amdgcn_mfma_f32_32x32x16_bf16(awu, bx, uac, 0, 0, 0);
    }
    __syncthreads();
    {   // transpose to TB [128 h'][128 B] @0, then coalesced plane write
        char* TB = smem;
#pragma unroll
        for (int r = 0; r < 16; ++r) {
            const int hv = wh*32 + (r & 3) + 8*(r >> 2) + 4*kg;
            const unsigned sw = (unsigned)(hv & 7) << 4;
            *(unsigned short*)(TB + hv*128        + ((ii*2) ^ sw)) = f2bf(vac[r]);
            *(unsigned short*)(TB + (hv + 64)*128 + ((ii*2) ^ sw)) = f2bf(uac[r]);
        }
    }
    __syncthreads();
    {
        const int hh = t >> 1, q = t & 1;
        const char* tb = smem + hh*128;
        const unsigned sw = (unsigned)(hh & 7) << 4;
        unsigned short* g = ovuT + ((size_t)(b*128 + hh))*1024 + i0g + q*32;
#pragma unroll
        for (int gg = 0; gg < 4; ++gg) {
            u32x4 v = *(const u32x4*)(tb + ((q*64 + gg*16) ^ sw));
            *(u32x4*)(g + gg*8) = v;
        }
    }
}

// ---------------------------------------------------------------------------
// finalize: logits[h] = ( colsum(P)·v3 + sum_i u3 ) / 1024; out = softmax.
__global__ __launch_bounds__(256)
void finalize(const float* __restrict__ pcol, const unsigned short* __restrict__ vuT3,
              float* __restrict__ out)
{
    __shared__ float red[2056];
    const int b = blockIdx.x, t = threadIdx.x;
    const int j0 = t * 4;
    f32x4 cs = {0.f, 0.f, 0.f, 0.f};
    for (int p = 0; p < 64; ++p)
        cs += *(const f32x4*)(pcol + ((size_t)(b*64 + p))*1024 + j0);
    float lv[4], lu[4];
#pragma unroll
    for (int h = 0; h < 4; ++h) {
        const unsigned short* vr = vuT3 + ((size_t)(b*128 + h))*1024 + j0;
        lv[h] = cs[0]*bf2f(vr[0]) + cs[1]*bf2f(vr[1]) + cs[2]*bf2f(vr[2]) + cs[3]*bf2f(vr[3]);
        const unsigned short* ur = vuT3 + ((size_t)(b*128 + 64 + h))*1024 + j0;
        lu[h] = bf2f(ur[0]) + bf2f(ur[1]) + bf2f(ur[2]) + bf2f(ur[3]);
    }
#pragma unroll
    for (int q = 0; q < 4; ++q) { red[t*8 + q] = lv[q]; red[t*8 + 4 + q] = lu[q]; }
    __syncthreads();
    if (t < 8) {
        float s = 0.f;
        for (int k = 0; k < 256; ++k) s += red[k*8 + t];
        red[2048 + t] = s;
    }
    __syncthreads();
    if (t == 0) {
        float v[4];
#pragma unroll
        for (int h = 0; h < 4; ++h) v[h] = (red[2048 + h] + red[2048 + 4 + h]) * (1.f / 1024.f);
        const float m = fmaxf(fmaxf(v[0], v[1]), fmaxf(v[2], v[3]));
        float e[4], se = 0.f;
#pragma unroll
        for (int h = 0; h < 4; ++h) { e[h] = __expf(v[h] - m); se += e[h]; }
        const float inv = 1.f / se;
#pragma unroll
        for (int h = 0; h < 4; ++h) out[b*4 + h] = e[h] * inv;
    }
}

extern "C" void kernel_launch(void* const* d_in, const int* in_sizes, int n_in,
                              void* d_out, int out_size, void* d_ws, size_t ws_size,
                              hipStream_t stream)
{
    const float* x   = (const float*)d_in[0];
    const float* co  = (const float*)d_in[1];
    const float* psq = (const float*)d_in[2];
    const float* W0  = (const float*)d_in[3];
    const float* W1  = (const float*)d_in[4];
    const float* W2  = (const float*)d_in[5];
    const float* W3  = (const float*)d_in[6];
    const float* b0  = (const float*)d_in[7];
    const float* b1  = (const float*)d_in[8];
    const float* b2  = (const float*)d_in[9];
    const float* b3  = (const float*)d_in[10];
    const float* g0  = (const float*)d_in[11];
    const float* be0 = (const float*)d_in[12];
    const float* g1  = (const float*)d_in[13];
    const float* be1 = (const float*)d_in[14];
    const float* g2  = (const float*)d_in[15];
    const float* be2 = (const float*)d_in[16];

    char* ws = (char*)d_ws;
    const size_t MB = (size_t)1 << 20;
    unsigned short* P    = (unsigned short*)(ws);             // 64 MB
    float*          pcol = (float*)(ws + 64*MB);              // 8 MB
    unsigned short* vuA  = (unsigned short*)(ws + 72*MB);     // 8 MB
    unsigned short* vuB  = (unsigned short*)(ws + 80*MB);     // 8 MB
    unsigned short* wpk  = (unsigned short*)(ws + 88*MB);     // 100 KB

    prep<<<dim3(200), 256, 0, stream>>>(W0, W1, W2, W3, wpk);
    tgen<<<dim3(64, 32), 256, 0, stream>>>(co, psq, P, pcol);

    dim3 grid(16, 32);
    proj0<<<grid, 256, 0, stream>>>(x, wpk, b0, vuA);
    fspmm<<<grid, 256, 0, stream>>>(vuA, P, g0, be0, wpk + 2048,  b1, vuB);
    fspmm<<<grid, 256, 0, stream>>>(vuB, P, g1, be1, wpk + 18432, b2, vuA);
    fspmm<<<grid, 256, 0, stream>>>(vuA, P, g2, be2, wpk + 34816, b3, vuB);
    finalize<<<dim3(32), 256, 0, stream>>>(pcol, vuB, (float*)d_out);
}